// Round 4
// baseline (134.977 us; speedup 1.0000x reference)
//
#include <hip/hip_runtime.h>
#include <hip/hip_bf16.h>
#include <math.h>

// B=32, T=1024, C=256, HS=64. fp32 in/out, bf16 MFMA internally.
// proj: barrier-free, LDS-free GEMM, W converted fp32->bf16 in-reg (no prep
//       kernel). grid 1024 x 32 m-rows, 4 waves x 48 n each -> 16 waves/CU.
//       __launch_bounds__(256,4) caps VGPR<=128 (prevents unroll spills).
//       Outputs: fqk[m][0:64]=k, [64:128]=q*0.125*log2e ; vt[b][h][s]=v.
// attn: 4 waves/block on one 32-query tile; s-tiles strided across waves
//       (no-max base-2 flash => combine is a pure sum of o and l partials).
//       P^T through per-wave LDS, PV as O^T = V^T @ P^T. 2 barriers/block.

#define B_  32
#define T_  1024
#define C_  256
#define HS_ 64
#define QSCALE 0.1803368801111204f   // 0.125 * log2(e)

typedef __attribute__((ext_vector_type(8))) short bf16x8;
typedef __attribute__((ext_vector_type(4))) float f32x4;

static __device__ __forceinline__ unsigned short f2bf(float f) {
    unsigned u = __builtin_bit_cast(unsigned, f);
    u += 0x7FFFu + ((u >> 16) & 1u);               // RNE
    return (unsigned short)(u >> 16);
}
// pack two floats to packed bf16 pair (round-half-up; 2 adds + 1 v_perm)
static __device__ __forceinline__ unsigned pack_bf2(float a, float b) {
    unsigned ua = __builtin_bit_cast(unsigned, a) + 0x8000u;
    unsigned ub = __builtin_bit_cast(unsigned, b) + 0x8000u;
    return __builtin_amdgcn_perm(ub, ua, 0x07060302u);  // [ua.hi16, ub.hi16]
}
static __device__ __forceinline__ bf16x8 cvt8(const float* p, float sc) {
    float4 v0 = *(const float4*)p;
    float4 v1 = *(const float4*)(p + 4);
    union { bf16x8 v; unsigned u[4]; } t;
    t.u[0] = pack_bf2(v0.x * sc, v0.y * sc);
    t.u[1] = pack_bf2(v0.z * sc, v0.w * sc);
    t.u[2] = pack_bf2(v1.x * sc, v1.y * sc);
    t.u[3] = pack_bf2(v1.z * sc, v1.w * sc);
    return t.v;
}
static __device__ __forceinline__ float fexp2(float x) {
#if __has_builtin(__builtin_amdgcn_exp2f)
    return __builtin_amdgcn_exp2f(x);
#else
    return exp2f(x);
#endif
}

// ---------------- proj: barrier-free bf16 MFMA GEMM ----------------
// grid 1024 (32 m-rows each), block 256 = 4 waves; wave w: n in [48w, 48w+48)
__global__ __launch_bounds__(256, 4) void proj_kernel(
    const float* __restrict__ x,
    const float* __restrict__ Wk, const float* __restrict__ Wq,
    const float* __restrict__ Wv,
    unsigned short* __restrict__ fqk, unsigned short* __restrict__ vt)
{
    const int tid = threadIdx.x;
    const int lane = tid & 63, w = tid >> 6;
    const int q4 = lane >> 4, l15 = lane & 15;
    const int m0 = blockIdx.x * 32;

    // per-n-tile W source row pointers (+ scale), lane row = l15
    const float* wrow[3];
    float wsc[3];
    #pragma unroll
    for (int nt = 0; nt < 3; ++nt) {
        const int nb = 48 * w + nt * 16;
        if (nb < 64)       { wrow[nt] = &Wk[(size_t)(nb      + l15) * C_]; wsc[nt] = 1.0f; }
        else if (nb < 128) { wrow[nt] = &Wq[(size_t)(nb - 64 + l15) * C_]; wsc[nt] = QSCALE; }
        else               { wrow[nt] = &Wv[(size_t)(nb - 128 + l15) * C_]; wsc[nt] = 1.0f; }
    }
    const float* xrow0 = &x[(size_t)(m0 + l15) * C_ + q4 * 8];
    const float* xrow1 = xrow0 + (size_t)16 * C_;

    f32x4 acc[3][2];
    #pragma unroll
    for (int nt = 0; nt < 3; ++nt)
        #pragma unroll
        for (int mt = 0; mt < 2; ++mt) acc[nt][mt] = (f32x4)0.0f;

    #pragma unroll 2
    for (int c0 = 0; c0 < C_; c0 += 32) {
        bf16x8 bx0 = cvt8(xrow0 + c0, 1.0f);
        bf16x8 bx1 = cvt8(xrow1 + c0, 1.0f);
        #pragma unroll
        for (int nt = 0; nt < 3; ++nt) {
            bf16x8 a = cvt8(wrow[nt] + c0 + q4 * 8, wsc[nt]);
            acc[nt][0] = __builtin_amdgcn_mfma_f32_16x16x32_bf16(a, bx0, acc[nt][0], 0, 0, 0);
            acc[nt][1] = __builtin_amdgcn_mfma_f32_16x16x32_bf16(a, bx1, acc[nt][1], 0, 0, 0);
        }
    }

    #pragma unroll
    for (int nt = 0; nt < 3; ++nt) {
        const int nbase = 48 * w + nt * 16 + q4 * 4;
        #pragma unroll
        for (int mt = 0; mt < 2; ++mt) {
            const int m = m0 + mt * 16 + l15;
            f32x4 v = acc[nt][mt];
            if (nbase < 128) {       // k | q -> fused row-major [m][128]
                uint2 o = make_uint2(pack_bf2(v.x, v.y), pack_bf2(v.z, v.w));
                *(uint2*)&fqk[(size_t)m * 128 + nbase] = o;
            } else {                 // v -> transposed vt[b][h][s]
                const int batch = m >> 10, s = m & 1023, h = nbase - 128;
                vt[((size_t)batch * 64 + h + 0) * 1024 + s] = f2bf(v.x);
                vt[((size_t)batch * 64 + h + 1) * 1024 + s] = f2bf(v.y);
                vt[((size_t)batch * 64 + h + 2) * 1024 + s] = f2bf(v.z);
                vt[((size_t)batch * 64 + h + 3) * 1024 + s] = f2bf(v.w);
            }
        }
    }
}

// ---------------- attention: 4-wave split-s flash, no-max, base-2 ----------------
// grid 1024 = 32 batches x 32 q-tiles (heavy-first); block 256 = 4 waves
__global__ __launch_bounds__(256) void attn_kernel(
    const unsigned short* __restrict__ fqk,
    const unsigned short* __restrict__ vt,
    float* __restrict__ out)
{
    __shared__ __align__(16) char smem[34816];   // Ps[4][32][72] (18.4K) U ocomb(32K)+lcomb(2K)

    const int tid = threadIdx.x;
    const int lane = tid & 63, w = tid >> 6;
    const int q4 = lane >> 4, l15 = lane & 15;
    const int batch = blockIdx.x & 31;
    const int qt = 31 - (blockIdx.x >> 5);
    const int q0 = qt * 32;
    const int ns = (qt >> 1) + 1;

    unsigned short (*Ps)[72] = (unsigned short(*)[72])(smem + w * 4608);

    // Q B-frags (shared by all 4 waves; L1-hot)
    bf16x8 qf[2][2];
    #pragma unroll
    for (int it = 0; it < 2; ++it)
        #pragma unroll
        for (int kc = 0; kc < 2; ++kc)
            qf[it][kc] = *(const bf16x8*)&fqk[(size_t)(batch * T_ + q0 + it * 16 + l15) * 128 + 64 + kc * 32 + q4 * 8];

    f32x4 o[4][2];
    #pragma unroll
    for (int ht = 0; ht < 4; ++ht)
        #pragma unroll
        for (int it = 0; it < 2; ++it) o[ht][it] = (f32x4)0.0f;
    float l[2] = {0.f, 0.f};

    const unsigned short* kbase = &fqk[(size_t)(batch * T_) * 128];
    const unsigned short* vbase = &vt[(size_t)batch * 64 * 1024];

    for (int st = w; st < ns; st += 4) {
        const int s0 = st * 64;
        const bool last = (st == ns - 1);
        #pragma unroll
        for (int hf = 0; hf < 2; ++hf) {
            const int sh = s0 + hf * 32;
            // K A-frags for this 32-s half
            bf16x8 ak[2][2];
            #pragma unroll
            for (int st16 = 0; st16 < 2; ++st16)
                #pragma unroll
                for (int kc = 0; kc < 2; ++kc)
                    ak[st16][kc] = *(const bf16x8*)&kbase[(size_t)(sh + st16 * 16 + l15) * 128 + kc * 32 + q4 * 8];
            // V^T A-frags for this half
            bf16x8 av[4];
            #pragma unroll
            for (int ht = 0; ht < 4; ++ht)
                av[ht] = *(const bf16x8*)&vbase[(size_t)(ht * 16 + l15) * 1024 + sh + q4 * 8];
            // S^T = K @ Q^T
            f32x4 s[2][2];
            #pragma unroll
            for (int st16 = 0; st16 < 2; ++st16)
                #pragma unroll
                for (int it = 0; it < 2; ++it) {
                    f32x4 c = (f32x4)0.0f;
                    c = __builtin_amdgcn_mfma_f32_16x16x32_bf16(ak[st16][0], qf[it][0], c, 0, 0, 0);
                    c = __builtin_amdgcn_mfma_f32_16x16x32_bf16(ak[st16][1], qf[it][1], c, 0, 0, 0);
                    s[st16][it] = c;
                }
            // p = 2^s', accumulate l, write P^T (packed b64)
            #pragma unroll
            for (int st16 = 0; st16 < 2; ++st16)
                #pragma unroll
                for (int it = 0; it < 2; ++it) {
                    const int iloc = it * 16 + l15;
                    float p[4];
                    #pragma unroll
                    for (int r = 0; r < 4; ++r) {
                        float pv = fexp2(s[st16][it][r]);
                        if (last) {
                            int sl = sh + st16 * 16 + q4 * 4 + r;
                            if (sl > q0 + iloc) pv = 0.0f;   // causal
                        }
                        p[r] = pv;
                        l[it] += pv;
                    }
                    uint2 pw = make_uint2(pack_bf2(p[0], p[1]), pack_bf2(p[2], p[3]));
                    *(uint2*)&Ps[iloc][hf * 32 + st16 * 16 + q4 * 4] = pw;
                }
            // PV: O^T += V^T @ P^T (single-wave LDS round trip, no barrier)
            #pragma unroll
            for (int it = 0; it < 2; ++it) {
                bf16x8 bp = *(const bf16x8*)&Ps[it * 16 + l15][hf * 32 + q4 * 8];
                #pragma unroll
                for (int ht = 0; ht < 4; ++ht)
                    o[ht][it] = __builtin_amdgcn_mfma_f32_16x16x32_bf16(av[ht], bp, o[ht][it], 0, 0, 0);
            }
        }
    }

    // wave-internal l reduce over quads (disjoint s per quad)
    #pragma unroll
    for (int it = 0; it < 2; ++it) {
        l[it] += __shfl_xor(l[it], 16);
        l[it] += __shfl_xor(l[it], 32);
    }

    __syncthreads();   // all waves done with Ps before combine-buffer reuse
    float4* ocomb = (float4*)smem;                 // [w][ht][it][lane]
    float*  lcomb = (float*)(smem + 32768);        // [w][it][lane]
    #pragma unroll
    for (int ht = 0; ht < 4; ++ht)
        #pragma unroll
        for (int it = 0; it < 2; ++it) {
            f32x4 v = o[ht][it];
            ocomb[((w * 4 + ht) * 2 + it) * 64 + lane] = make_float4(v.x, v.y, v.z, v.w);
        }
    #pragma unroll
    for (int it = 0; it < 2; ++it) lcomb[(w * 2 + it) * 64 + lane] = l[it];
    __syncthreads();

    // wave w reduces head-tile ht = w and stores
    #pragma unroll
    for (int it = 0; it < 2; ++it) {
        float4 a = make_float4(0.f, 0.f, 0.f, 0.f);
        float lt = 0.f;
        #pragma unroll
        for (int src = 0; src < 4; ++src) {
            float4 t = ocomb[((src * 4 + w) * 2 + it) * 64 + lane];
            a.x += t.x; a.y += t.y; a.z += t.z; a.w += t.w;
            lt += lcomb[(src * 2 + it) * 64 + lane];
        }
        float inv = 1.0f / lt;
        float4 res = make_float4(a.x * inv, a.y * inv, a.z * inv, a.w * inv);
        *(float4*)&out[(size_t)(batch * T_ + q0 + it * 16 + l15) * HS_ + w * 16 + q4 * 4] = res;
    }
}

extern "C" void kernel_launch(void* const* d_in, const int* in_sizes, int n_in,
                              void* d_out, int out_size, void* d_ws, size_t ws_size,
                              hipStream_t stream) {
    (void)in_sizes; (void)n_in; (void)out_size; (void)ws_size;
    const float* x  = (const float*)d_in[0];
    const float* Wk = (const float*)d_in[1];
    const float* Wq = (const float*)d_in[2];
    const float* Wv = (const float*)d_in[3];

    unsigned short* fqk = (unsigned short*)d_ws;                                   // 8 MB
    unsigned short* vtb = (unsigned short*)((char*)d_ws + (size_t)32768 * 128 * 2); // 4 MB

    hipLaunchKernelGGL(proj_kernel, dim3(1024), dim3(256), 0, stream,
                       x, Wk, Wq, Wv, fqk, vtb);
    hipLaunchKernelGGL(attn_kernel, dim3(1024), dim3(256), 0, stream,
                       fqk, vtb, (float*)d_out);
}

// Round 5
// 134.646 us; speedup vs baseline: 1.0025x; 1.0025x over previous
//
#include <hip/hip_runtime.h>
#include <hip/hip_bf16.h>
#include <math.h>

// B=32, T=1024, C=256, HS=64. fp32 in/out, bf16 MFMA internally.
// proj: barrier-free, LDS-free GEMM, W converted fp32->bf16 in-reg.
//       Depth-1 register software pipeline (ping-pong 10x float4) so ~20 b128
//       loads stay in flight; NO waves/EU cap (R4's (256,4) cap serialized the
//       load chain: VGPR=60, 44us, all pipes idle).
//       Outputs: fqk[m][0:64]=k, [64:128]=q*0.125*log2e ; vt[b][h][s]=v.
// attn: 4 waves/block on one 32-query tile; s-tiles strided across waves
//       (no-max base-2 flash => combine is a pure sum of o and l partials).
//       P^T through per-wave LDS, PV as O^T = V^T @ P^T. 2 barriers/block.

#define B_  32
#define T_  1024
#define C_  256
#define HS_ 64
#define QSCALE 0.1803368801111204f   // 0.125 * log2(e)

typedef __attribute__((ext_vector_type(8))) short bf16x8;
typedef __attribute__((ext_vector_type(4))) float f32x4;

static __device__ __forceinline__ unsigned short f2bf(float f) {
    unsigned u = __builtin_bit_cast(unsigned, f);
    u += 0x7FFFu + ((u >> 16) & 1u);               // RNE
    return (unsigned short)(u >> 16);
}
// pack two floats to packed bf16 pair (round-half-up; 2 adds + 1 v_perm)
static __device__ __forceinline__ unsigned pack_bf2(float a, float b) {
    unsigned ua = __builtin_bit_cast(unsigned, a) + 0x8000u;
    unsigned ub = __builtin_bit_cast(unsigned, b) + 0x8000u;
    return __builtin_amdgcn_perm(ub, ua, 0x07060302u);  // [ua.hi16, ub.hi16]
}
static __device__ __forceinline__ bf16x8 cvt8r(float4 v0, float4 v1) {
    union { bf16x8 v; unsigned u[4]; } t;
    t.u[0] = pack_bf2(v0.x, v0.y); t.u[1] = pack_bf2(v0.z, v0.w);
    t.u[2] = pack_bf2(v1.x, v1.y); t.u[3] = pack_bf2(v1.z, v1.w);
    return t.v;
}
static __device__ __forceinline__ bf16x8 cvt8rs(float4 v0, float4 v1, float sc) {
    union { bf16x8 v; unsigned u[4]; } t;
    t.u[0] = pack_bf2(v0.x * sc, v0.y * sc); t.u[1] = pack_bf2(v0.z * sc, v0.w * sc);
    t.u[2] = pack_bf2(v1.x * sc, v1.y * sc); t.u[3] = pack_bf2(v1.z * sc, v1.w * sc);
    return t.v;
}
static __device__ __forceinline__ float fexp2(float x) {
#if __has_builtin(__builtin_amdgcn_exp2f)
    return __builtin_amdgcn_exp2f(x);
#else
    return exp2f(x);
#endif
}

// ---------------- proj: barrier-free bf16 MFMA GEMM, reg-pipelined ----------------
// grid 1024 (32 m-rows each), block 256 = 4 waves; wave w: n in [48w, 48w+48)
__global__ __launch_bounds__(256) void proj_kernel(
    const float* __restrict__ x,
    const float* __restrict__ Wk, const float* __restrict__ Wq,
    const float* __restrict__ Wv,
    unsigned short* __restrict__ fqk, unsigned short* __restrict__ vt)
{
    const int tid = threadIdx.x;
    const int lane = tid & 63, w = tid >> 6;
    const int q4 = lane >> 4, l15 = lane & 15;
    const int m0 = blockIdx.x * 32;

    // per-n-tile W source row pointers (+ scale), lane row = l15, col base q4*8
    const float* wp[3];
    float wsc[3];
    #pragma unroll
    for (int nt = 0; nt < 3; ++nt) {
        const int nb = 48 * w + nt * 16;
        if (nb < 64)       { wp[nt] = &Wk[(size_t)(nb       + l15) * C_ + q4 * 8]; wsc[nt] = 1.0f; }
        else if (nb < 128) { wp[nt] = &Wq[(size_t)(nb - 64  + l15) * C_ + q4 * 8]; wsc[nt] = QSCALE; }
        else               { wp[nt] = &Wv[(size_t)(nb - 128 + l15) * C_ + q4 * 8]; wsc[nt] = 1.0f; }
    }
    const float* xrow0 = &x[(size_t)(m0 + l15) * C_ + q4 * 8];
    const float* xrow1 = xrow0 + (size_t)16 * C_;

    f32x4 acc[3][2];
    #pragma unroll
    for (int nt = 0; nt < 3; ++nt)
        #pragma unroll
        for (int mt = 0; mt < 2; ++mt) acc[nt][mt] = (f32x4)0.0f;

    float4 A[10], Bv[10];
    auto load10 = [&](float4* d, int c0) {
        d[0] = *(const float4*)(xrow0 + c0);
        d[1] = *(const float4*)(xrow0 + c0 + 4);
        d[2] = *(const float4*)(xrow1 + c0);
        d[3] = *(const float4*)(xrow1 + c0 + 4);
        #pragma unroll
        for (int nt = 0; nt < 3; ++nt) {
            d[4 + 2 * nt] = *(const float4*)(wp[nt] + c0);
            d[5 + 2 * nt] = *(const float4*)(wp[nt] + c0 + 4);
        }
    };
    auto step = [&](const float4* d) {
        bf16x8 bx0 = cvt8r(d[0], d[1]);
        bf16x8 bx1 = cvt8r(d[2], d[3]);
        #pragma unroll
        for (int nt = 0; nt < 3; ++nt) {
            bf16x8 a = cvt8rs(d[4 + 2 * nt], d[5 + 2 * nt], wsc[nt]);
            acc[nt][0] = __builtin_amdgcn_mfma_f32_16x16x32_bf16(a, bx0, acc[nt][0], 0, 0, 0);
            acc[nt][1] = __builtin_amdgcn_mfma_f32_16x16x32_bf16(a, bx1, acc[nt][1], 0, 0, 0);
        }
    };

    load10(A, 0);
    #pragma unroll
    for (int c0 = 0; c0 < C_; c0 += 64) {
        load10(Bv, c0 + 32);
        step(A);
        if (c0 + 64 < C_) load10(A, c0 + 64);
        step(Bv);
    }

    #pragma unroll
    for (int nt = 0; nt < 3; ++nt) {
        const int nbase = 48 * w + nt * 16 + q4 * 4;
        #pragma unroll
        for (int mt = 0; mt < 2; ++mt) {
            const int m = m0 + mt * 16 + l15;
            f32x4 v = acc[nt][mt];
            if (nbase < 128) {       // k | q -> fused row-major [m][128]
                uint2 o = make_uint2(pack_bf2(v.x, v.y), pack_bf2(v.z, v.w));
                *(uint2*)&fqk[(size_t)m * 128 + nbase] = o;
            } else {                 // v -> transposed vt[b][h][s]
                const int batch = m >> 10, s = m & 1023, h = nbase - 128;
                vt[((size_t)batch * 64 + h + 0) * 1024 + s] = f2bf(v.x);
                vt[((size_t)batch * 64 + h + 1) * 1024 + s] = f2bf(v.y);
                vt[((size_t)batch * 64 + h + 2) * 1024 + s] = f2bf(v.z);
                vt[((size_t)batch * 64 + h + 3) * 1024 + s] = f2bf(v.w);
            }
        }
    }
}

// ---------------- attention: 4-wave split-s flash, no-max, base-2 ----------------
// grid 1024 = 32 batches x 32 q-tiles (heavy-first); block 256 = 4 waves
__global__ __launch_bounds__(256) void attn_kernel(
    const unsigned short* __restrict__ fqk,
    const unsigned short* __restrict__ vt,
    float* __restrict__ out)
{
    __shared__ __align__(16) char smem[34816];   // Ps[4][32][72] (18.4K) U ocomb(32K)+lcomb(2K)

    const int tid = threadIdx.x;
    const int lane = tid & 63, w = tid >> 6;
    const int q4 = lane >> 4, l15 = lane & 15;
    const int batch = blockIdx.x & 31;
    const int qt = 31 - (blockIdx.x >> 5);
    const int q0 = qt * 32;
    const int ns = (qt >> 1) + 1;

    unsigned short (*Ps)[72] = (unsigned short(*)[72])(smem + w * 4608);

    // Q B-frags (shared by all 4 waves; L1-hot)
    bf16x8 qf[2][2];
    #pragma unroll
    for (int it = 0; it < 2; ++it)
        #pragma unroll
        for (int kc = 0; kc < 2; ++kc)
            qf[it][kc] = *(const bf16x8*)&fqk[(size_t)(batch * T_ + q0 + it * 16 + l15) * 128 + 64 + kc * 32 + q4 * 8];

    f32x4 o[4][2];
    #pragma unroll
    for (int ht = 0; ht < 4; ++ht)
        #pragma unroll
        for (int it = 0; it < 2; ++it) o[ht][it] = (f32x4)0.0f;
    float l[2] = {0.f, 0.f};

    const unsigned short* kbase = &fqk[(size_t)(batch * T_) * 128];
    const unsigned short* vbase = &vt[(size_t)batch * 64 * 1024];

    for (int st = w; st < ns; st += 4) {
        const int s0 = st * 64;
        const bool last = (st == ns - 1);
        #pragma unroll
        for (int hf = 0; hf < 2; ++hf) {
            const int sh = s0 + hf * 32;
            // K A-frags for this 32-s half
            bf16x8 ak[2][2];
            #pragma unroll
            for (int st16 = 0; st16 < 2; ++st16)
                #pragma unroll
                for (int kc = 0; kc < 2; ++kc)
                    ak[st16][kc] = *(const bf16x8*)&kbase[(size_t)(sh + st16 * 16 + l15) * 128 + kc * 32 + q4 * 8];
            // V^T A-frags for this half
            bf16x8 av[4];
            #pragma unroll
            for (int ht = 0; ht < 4; ++ht)
                av[ht] = *(const bf16x8*)&vbase[(size_t)(ht * 16 + l15) * 1024 + sh + q4 * 8];
            // S^T = K @ Q^T
            f32x4 s[2][2];
            #pragma unroll
            for (int st16 = 0; st16 < 2; ++st16)
                #pragma unroll
                for (int it = 0; it < 2; ++it) {
                    f32x4 c = (f32x4)0.0f;
                    c = __builtin_amdgcn_mfma_f32_16x16x32_bf16(ak[st16][0], qf[it][0], c, 0, 0, 0);
                    c = __builtin_amdgcn_mfma_f32_16x16x32_bf16(ak[st16][1], qf[it][1], c, 0, 0, 0);
                    s[st16][it] = c;
                }
            // p = 2^s', accumulate l, write P^T (packed b64)
            #pragma unroll
            for (int st16 = 0; st16 < 2; ++st16)
                #pragma unroll
                for (int it = 0; it < 2; ++it) {
                    const int iloc = it * 16 + l15;
                    float p[4];
                    #pragma unroll
                    for (int r = 0; r < 4; ++r) {
                        float pv = fexp2(s[st16][it][r]);
                        if (last) {
                            int sl = sh + st16 * 16 + q4 * 4 + r;
                            if (sl > q0 + iloc) pv = 0.0f;   // causal
                        }
                        p[r] = pv;
                        l[it] += pv;
                    }
                    uint2 pw = make_uint2(pack_bf2(p[0], p[1]), pack_bf2(p[2], p[3]));
                    *(uint2*)&Ps[iloc][hf * 32 + st16 * 16 + q4 * 4] = pw;
                }
            // PV: O^T += V^T @ P^T (single-wave LDS round trip, no barrier)
            #pragma unroll
            for (int it = 0; it < 2; ++it) {
                bf16x8 bp = *(const bf16x8*)&Ps[it * 16 + l15][hf * 32 + q4 * 8];
                #pragma unroll
                for (int ht = 0; ht < 4; ++ht)
                    o[ht][it] = __builtin_amdgcn_mfma_f32_16x16x32_bf16(av[ht], bp, o[ht][it], 0, 0, 0);
            }
        }
    }

    // wave-internal l reduce over quads (disjoint s per quad)
    #pragma unroll
    for (int it = 0; it < 2; ++it) {
        l[it] += __shfl_xor(l[it], 16);
        l[it] += __shfl_xor(l[it], 32);
    }

    __syncthreads();   // all waves done with Ps before combine-buffer reuse
    float4* ocomb = (float4*)smem;                 // [w][ht][it][lane]
    float*  lcomb = (float*)(smem + 32768);        // [w][it][lane]
    #pragma unroll
    for (int ht = 0; ht < 4; ++ht)
        #pragma unroll
        for (int it = 0; it < 2; ++it) {
            f32x4 v = o[ht][it];
            ocomb[((w * 4 + ht) * 2 + it) * 64 + lane] = make_float4(v.x, v.y, v.z, v.w);
        }
    #pragma unroll
    for (int it = 0; it < 2; ++it) lcomb[(w * 2 + it) * 64 + lane] = l[it];
    __syncthreads();

    // wave w reduces head-tile ht = w and stores
    #pragma unroll
    for (int it = 0; it < 2; ++it) {
        float4 a = make_float4(0.f, 0.f, 0.f, 0.f);
        float lt = 0.f;
        #pragma unroll
        for (int src = 0; src < 4; ++src) {
            float4 t = ocomb[((src * 4 + w) * 2 + it) * 64 + lane];
            a.x += t.x; a.y += t.y; a.z += t.z; a.w += t.w;
            lt += lcomb[(src * 2 + it) * 64 + lane];
        }
        float inv = 1.0f / lt;
        float4 res = make_float4(a.x * inv, a.y * inv, a.z * inv, a.w * inv);
        *(float4*)&out[(size_t)(batch * T_ + q0 + it * 16 + l15) * HS_ + w * 16 + q4 * 4] = res;
    }
}

extern "C" void kernel_launch(void* const* d_in, const int* in_sizes, int n_in,
                              void* d_out, int out_size, void* d_ws, size_t ws_size,
                              hipStream_t stream) {
    (void)in_sizes; (void)n_in; (void)out_size; (void)ws_size;
    const float* x  = (const float*)d_in[0];
    const float* Wk = (const float*)d_in[1];
    const float* Wq = (const float*)d_in[2];
    const float* Wv = (const float*)d_in[3];

    unsigned short* fqk = (unsigned short*)d_ws;                                   // 8 MB
    unsigned short* vtb = (unsigned short*)((char*)d_ws + (size_t)32768 * 128 * 2); // 4 MB

    hipLaunchKernelGGL(proj_kernel, dim3(1024), dim3(256), 0, stream,
                       x, Wk, Wq, Wv, fqk, vtb);
    hipLaunchKernelGGL(attn_kernel, dim3(1024), dim3(256), 0, stream,
                       fqk, vtb, (float*)d_out);
}

// Round 6
// 115.209 us; speedup vs baseline: 1.1716x; 1.1687x over previous
//
#include <hip/hip_runtime.h>
#include <hip/hip_bf16.h>
#include <math.h>

// B=32, T=1024, C=256, HS=64. fp32 in/out, bf16 MFMA internally.
// prep: W -> bf16 wbf[192][256] (k | q*0.125*log2e | v rows), once (~96 KB).
// proj: x tile (32 rows x 256 fp32 = 32 KB) staged via async
//       global_load_lds width=16 (1 row = 1 KB per call, LDS pitch 1040 B so
//       frag ds_reads are conflict-free-equivalent). One barrier per block.
//       B-frags: LDS fp32 -> bf16 in-reg. A-frags: bf16x8 straight from
//       L2-hot wbf, rotating 1-step prefetch. 4 blocks/CU, grid fully resident.
//       (R4/R5 lesson: synchronous VGPR loads get re-serialized by the
//       pressure scheduler - VGPR pinned at 60, 44 us, all pipes idle.
//       Async DMA-to-LDS is immune: the only wait is the barrier.)
// attn: 4 waves/block on one 32-query tile; s-tiles strided across waves
//       (no-max base-2 flash => combine is a pure sum of o and l partials).
//       P^T through per-wave LDS, PV as O^T = V^T @ P^T. 2 barriers/block.

#define B_  32
#define T_  1024
#define C_  256
#define HS_ 64
#define QSCALE 0.1803368801111204f   // 0.125 * log2(e)

typedef __attribute__((ext_vector_type(8))) short bf16x8;
typedef __attribute__((ext_vector_type(4))) float f32x4;

static __device__ __forceinline__ unsigned short f2bf(float f) {
    unsigned u = __builtin_bit_cast(unsigned, f);
    u += 0x7FFFu + ((u >> 16) & 1u);               // RNE
    return (unsigned short)(u >> 16);
}
// pack two floats to packed bf16 pair (round-half-up; 2 adds + 1 v_perm)
static __device__ __forceinline__ unsigned pack_bf2(float a, float b) {
    unsigned ua = __builtin_bit_cast(unsigned, a) + 0x8000u;
    unsigned ub = __builtin_bit_cast(unsigned, b) + 0x8000u;
    return __builtin_amdgcn_perm(ub, ua, 0x07060302u);  // [ua.hi16, ub.hi16]
}
static __device__ __forceinline__ bf16x8 cvt8r(float4 v0, float4 v1) {
    union { bf16x8 v; unsigned u[4]; } t;
    t.u[0] = pack_bf2(v0.x, v0.y); t.u[1] = pack_bf2(v0.z, v0.w);
    t.u[2] = pack_bf2(v1.x, v1.y); t.u[3] = pack_bf2(v1.z, v1.w);
    return t.v;
}
static __device__ __forceinline__ float fexp2(float x) {
#if __has_builtin(__builtin_amdgcn_exp2f)
    return __builtin_amdgcn_exp2f(x);
#else
    return exp2f(x);
#endif
}
// async global -> LDS, 16 B per lane (lane i lands at l + 16*i)
static __device__ __forceinline__ void gl_lds16(const float* g, void* l) {
    __builtin_amdgcn_global_load_lds(
        (const __attribute__((address_space(1))) unsigned*)g,
        (__attribute__((address_space(3))) unsigned*)l, 16, 0, 0);
}

// ---------------- prep: W -> bf16 (q rows pre-scaled) ----------------
__global__ __launch_bounds__(256) void prep_kernel(
    const float* __restrict__ Wk, const float* __restrict__ Wq,
    const float* __restrict__ Wv, unsigned short* __restrict__ wbf)
{
    const int idx = blockIdx.x * 256 + threadIdx.x;   // 0..12287 float4s
    const int row = idx >> 6, c4 = (idx & 63) << 2;
    const float* src; float sc = 1.0f;
    if (row < 64)       src = &Wk[(size_t)row * C_];
    else if (row < 128) { src = &Wq[(size_t)(row - 64) * C_]; sc = QSCALE; }
    else                src = &Wv[(size_t)(row - 128) * C_];
    float4 v = *(const float4*)&src[c4];
    uint2 o = make_uint2(pack_bf2(v.x * sc, v.y * sc), pack_bf2(v.z * sc, v.w * sc));
    *(uint2*)&wbf[(size_t)row * C_ + c4] = o;
}

// ---------------- proj: async-staged bf16 MFMA GEMM ----------------
// grid 1024 (32 m-rows each), block 256 = 4 waves; wave w: n in [48w, 48w+48)
#define XPITCH 1040   // bytes per x row in LDS (1024 + 16 pad; 260 dw = 4 mod 32)
__global__ __launch_bounds__(256) void proj_kernel(
    const float* __restrict__ x, const unsigned short* __restrict__ wbf,
    unsigned short* __restrict__ fqk, unsigned short* __restrict__ vt)
{
    __shared__ __align__(16) char xls[32 * XPITCH];   // 33280 B -> 4 blocks/CU

    const int tid = threadIdx.x;
    const int lane = tid & 63, w = tid >> 6;
    const int q4 = lane >> 4, l15 = lane & 15;
    const int m0 = blockIdx.x * 32;

    // stage: wave w DMAs rows 8w..8w+7 (1 KB per call, contiguous per row)
    {
        const float* gbase = &x[(size_t)(m0 + 8 * w) * C_ + lane * 4];
        #pragma unroll
        for (int j = 0; j < 8; ++j)
            gl_lds16(gbase + (size_t)j * C_, xls + (8 * w + j) * XPITCH);
    }

    // A-frag source rows in wbf (bf16, pre-scaled)
    const unsigned short* wrow = &wbf[(size_t)(48 * w + l15) * C_ + q4 * 8];

    f32x4 acc[3][2];
    #pragma unroll
    for (int nt = 0; nt < 3; ++nt)
        #pragma unroll
        for (int mt = 0; mt < 2; ++mt) acc[nt][mt] = (f32x4)0.0f;

    // prefetch first A-frags (overlaps the DMA)
    bf16x8 aw[3];
    #pragma unroll
    for (int nt = 0; nt < 3; ++nt)
        aw[nt] = *(const bf16x8*)&wrow[(size_t)nt * 16 * C_];

    __syncthreads();   // DMA complete (barrier drains vmcnt)

    #pragma unroll
    for (int ks = 0; ks < 8; ++ks) {
        // B-frags from LDS (fp32 -> bf16 in-reg)
        bf16x8 bx[2];
        #pragma unroll
        for (int mt = 0; mt < 2; ++mt) {
            const float* p = (const float*)(xls + (mt * 16 + l15) * XPITCH
                                            + (ks * 32 + q4 * 8) * 4);
            float4 v0 = *(const float4*)p;
            float4 v1 = *(const float4*)(p + 4);
            bx[mt] = cvt8r(v0, v1);
        }
        bf16x8 awn[3];
        if (ks < 7) {
            #pragma unroll
            for (int nt = 0; nt < 3; ++nt)
                awn[nt] = *(const bf16x8*)&wrow[(size_t)nt * 16 * C_ + (ks + 1) * 32];
        }
        #pragma unroll
        for (int nt = 0; nt < 3; ++nt) {
            acc[nt][0] = __builtin_amdgcn_mfma_f32_16x16x32_bf16(aw[nt], bx[0], acc[nt][0], 0, 0, 0);
            acc[nt][1] = __builtin_amdgcn_mfma_f32_16x16x32_bf16(aw[nt], bx[1], acc[nt][1], 0, 0, 0);
        }
        #pragma unroll
        for (int nt = 0; nt < 3; ++nt) aw[nt] = awn[nt];
    }

    #pragma unroll
    for (int nt = 0; nt < 3; ++nt) {
        const int nbase = 48 * w + nt * 16 + q4 * 4;
        #pragma unroll
        for (int mt = 0; mt < 2; ++mt) {
            const int m = m0 + mt * 16 + l15;
            f32x4 v = acc[nt][mt];
            if (nbase < 128) {       // k | q -> fused row-major [m][128]
                uint2 o = make_uint2(pack_bf2(v.x, v.y), pack_bf2(v.z, v.w));
                *(uint2*)&fqk[(size_t)m * 128 + nbase] = o;
            } else {                 // v -> transposed vt[b][h][s]
                const int batch = m >> 10, s = m & 1023, h = nbase - 128;
                vt[((size_t)batch * 64 + h + 0) * 1024 + s] = f2bf(v.x);
                vt[((size_t)batch * 64 + h + 1) * 1024 + s] = f2bf(v.y);
                vt[((size_t)batch * 64 + h + 2) * 1024 + s] = f2bf(v.z);
                vt[((size_t)batch * 64 + h + 3) * 1024 + s] = f2bf(v.w);
            }
        }
    }
}

// ---------------- attention: 4-wave split-s flash, no-max, base-2 ----------------
// grid 1024 = 32 batches x 32 q-tiles (heavy-first); block 256 = 4 waves
__global__ __launch_bounds__(256) void attn_kernel(
    const unsigned short* __restrict__ fqk,
    const unsigned short* __restrict__ vt,
    float* __restrict__ out)
{
    __shared__ __align__(16) char smem[34816];   // Ps[4][32][72] (18.4K) U ocomb(32K)+lcomb(2K)

    const int tid = threadIdx.x;
    const int lane = tid & 63, w = tid >> 6;
    const int q4 = lane >> 4, l15 = lane & 15;
    const int batch = blockIdx.x & 31;
    const int qt = 31 - (blockIdx.x >> 5);
    const int q0 = qt * 32;
    const int ns = (qt >> 1) + 1;

    unsigned short (*Ps)[72] = (unsigned short(*)[72])(smem + w * 4608);

    // Q B-frags (shared by all 4 waves; L1-hot)
    bf16x8 qf[2][2];
    #pragma unroll
    for (int it = 0; it < 2; ++it)
        #pragma unroll
        for (int kc = 0; kc < 2; ++kc)
            qf[it][kc] = *(const bf16x8*)&fqk[(size_t)(batch * T_ + q0 + it * 16 + l15) * 128 + 64 + kc * 32 + q4 * 8];

    f32x4 o[4][2];
    #pragma unroll
    for (int ht = 0; ht < 4; ++ht)
        #pragma unroll
        for (int it = 0; it < 2; ++it) o[ht][it] = (f32x4)0.0f;
    float l[2] = {0.f, 0.f};

    const unsigned short* kbase = &fqk[(size_t)(batch * T_) * 128];
    const unsigned short* vbase = &vt[(size_t)batch * 64 * 1024];

    for (int st = w; st < ns; st += 4) {
        const int s0 = st * 64;
        const bool last = (st == ns - 1);
        #pragma unroll
        for (int hf = 0; hf < 2; ++hf) {
            const int sh = s0 + hf * 32;
            // K A-frags for this 32-s half
            bf16x8 ak[2][2];
            #pragma unroll
            for (int st16 = 0; st16 < 2; ++st16)
                #pragma unroll
                for (int kc = 0; kc < 2; ++kc)
                    ak[st16][kc] = *(const bf16x8*)&kbase[(size_t)(sh + st16 * 16 + l15) * 128 + kc * 32 + q4 * 8];
            // V^T A-frags for this half
            bf16x8 av[4];
            #pragma unroll
            for (int ht = 0; ht < 4; ++ht)
                av[ht] = *(const bf16x8*)&vbase[(size_t)(ht * 16 + l15) * 1024 + sh + q4 * 8];
            // S^T = K @ Q^T
            f32x4 s[2][2];
            #pragma unroll
            for (int st16 = 0; st16 < 2; ++st16)
                #pragma unroll
                for (int it = 0; it < 2; ++it) {
                    f32x4 c = (f32x4)0.0f;
                    c = __builtin_amdgcn_mfma_f32_16x16x32_bf16(ak[st16][0], qf[it][0], c, 0, 0, 0);
                    c = __builtin_amdgcn_mfma_f32_16x16x32_bf16(ak[st16][1], qf[it][1], c, 0, 0, 0);
                    s[st16][it] = c;
                }
            // p = 2^s', accumulate l, write P^T (packed b64)
            #pragma unroll
            for (int st16 = 0; st16 < 2; ++st16)
                #pragma unroll
                for (int it = 0; it < 2; ++it) {
                    const int iloc = it * 16 + l15;
                    float p[4];
                    #pragma unroll
                    for (int r = 0; r < 4; ++r) {
                        float pv = fexp2(s[st16][it][r]);
                        if (last) {
                            int sl = sh + st16 * 16 + q4 * 4 + r;
                            if (sl > q0 + iloc) pv = 0.0f;   // causal
                        }
                        p[r] = pv;
                        l[it] += pv;
                    }
                    uint2 pw = make_uint2(pack_bf2(p[0], p[1]), pack_bf2(p[2], p[3]));
                    *(uint2*)&Ps[iloc][hf * 32 + st16 * 16 + q4 * 4] = pw;
                }
            // PV: O^T += V^T @ P^T (single-wave LDS round trip, no barrier)
            #pragma unroll
            for (int it = 0; it < 2; ++it) {
                bf16x8 bp = *(const bf16x8*)&Ps[it * 16 + l15][hf * 32 + q4 * 8];
                #pragma unroll
                for (int ht = 0; ht < 4; ++ht)
                    o[ht][it] = __builtin_amdgcn_mfma_f32_16x16x32_bf16(av[ht], bp, o[ht][it], 0, 0, 0);
            }
        }
    }

    // wave-internal l reduce over quads (disjoint s per quad)
    #pragma unroll
    for (int it = 0; it < 2; ++it) {
        l[it] += __shfl_xor(l[it], 16);
        l[it] += __shfl_xor(l[it], 32);
    }

    __syncthreads();   // all waves done with Ps before combine-buffer reuse
    float4* ocomb = (float4*)smem;                 // [w][ht][it][lane]
    float*  lcomb = (float*)(smem + 32768);        // [w][it][lane]
    #pragma unroll
    for (int ht = 0; ht < 4; ++ht)
        #pragma unroll
        for (int it = 0; it < 2; ++it) {
            f32x4 v = o[ht][it];
            ocomb[((w * 4 + ht) * 2 + it) * 64 + lane] = make_float4(v.x, v.y, v.z, v.w);
        }
    #pragma unroll
    for (int it = 0; it < 2; ++it) lcomb[(w * 2 + it) * 64 + lane] = l[it];
    __syncthreads();

    // wave w reduces head-tile ht = w and stores
    #pragma unroll
    for (int it = 0; it < 2; ++it) {
        float4 a = make_float4(0.f, 0.f, 0.f, 0.f);
        float lt = 0.f;
        #pragma unroll
        for (int src = 0; src < 4; ++src) {
            float4 t = ocomb[((src * 4 + w) * 2 + it) * 64 + lane];
            a.x += t.x; a.y += t.y; a.z += t.z; a.w += t.w;
            lt += lcomb[(src * 2 + it) * 64 + lane];
        }
        float inv = 1.0f / lt;
        float4 res = make_float4(a.x * inv, a.y * inv, a.z * inv, a.w * inv);
        *(float4*)&out[(size_t)(batch * T_ + q0 + it * 16 + l15) * HS_ + w * 16 + q4 * 4] = res;
    }
}

extern "C" void kernel_launch(void* const* d_in, const int* in_sizes, int n_in,
                              void* d_out, int out_size, void* d_ws, size_t ws_size,
                              hipStream_t stream) {
    (void)in_sizes; (void)n_in; (void)out_size; (void)ws_size;
    const float* x  = (const float*)d_in[0];
    const float* Wk = (const float*)d_in[1];
    const float* Wq = (const float*)d_in[2];
    const float* Wv = (const float*)d_in[3];

    unsigned short* wbf = (unsigned short*)d_ws;                                   // 96 KB
    unsigned short* fqk = (unsigned short*)((char*)d_ws + 98304);                  // 8 MB
    unsigned short* vtb = (unsigned short*)((char*)d_ws + 98304 + (size_t)32768 * 128 * 2); // 4 MB

    hipLaunchKernelGGL(prep_kernel, dim3(48),   dim3(256), 0, stream, Wk, Wq, Wv, wbf);
    hipLaunchKernelGGL(proj_kernel, dim3(1024), dim3(256), 0, stream, x, wbf, fqk, vtb);
    hipLaunchKernelGGL(attn_kernel, dim3(1024), dim3(256), 0, stream, fqk, vtb, (float*)d_out);
}

// Round 7
// 108.644 us; speedup vs baseline: 1.2424x; 1.0604x over previous
//
#include <hip/hip_runtime.h>
#include <hip/hip_bf16.h>
#include <math.h>

// B=32, T=1024, C=256, HS=64. fp32 in/out, bf16 MFMA internally.
// prep: W -> bf16 wbf[192][256] (k | q*0.125*log2e | v rows), once (~96 KB).
// proj: x tile staged via async global_load_lds (pitch 1040), W A-frags from
//       L2-hot wbf. Outputs:
//       FQK frag-major chunk-pair layout: [mblk(2048)][cp(16)][r(16)][8] bf16,
//         cols 0..63 = k, 64..127 = q*0.125*log2e. Stores coalesced (8B x 16
//         lanes contiguous); attn reads are single b128 per lane, coalesced.
//       vt[b][h][s] = v transposed (scalar stores, 32B runs).
// attn: 4 waves/block, 32-query tile, s-tiles strided across waves (no-max
//       base-2 flash: combine is a pure sum). XCD-aware swizzle: batch =
//       4*(bx&7)+(slot&3) pins each batch's K/V (384 KB) to one XCD's L2.
//       P^T via per-wave LDS, PV as O^T = V^T @ P^T. 2 barriers/block.

#define B_  32
#define T_  1024
#define C_  256
#define HS_ 64
#define QSCALE 0.1803368801111204f   // 0.125 * log2(e)

typedef __attribute__((ext_vector_type(8))) short bf16x8;
typedef __attribute__((ext_vector_type(4))) float f32x4;

static __device__ __forceinline__ unsigned short f2bf(float f) {
    unsigned u = __builtin_bit_cast(unsigned, f);
    u += 0x7FFFu + ((u >> 16) & 1u);               // RNE
    return (unsigned short)(u >> 16);
}
// pack two floats to packed bf16 pair (round-half-up; 2 adds + 1 v_perm)
static __device__ __forceinline__ unsigned pack_bf2(float a, float b) {
    unsigned ua = __builtin_bit_cast(unsigned, a) + 0x8000u;
    unsigned ub = __builtin_bit_cast(unsigned, b) + 0x8000u;
    return __builtin_amdgcn_perm(ub, ua, 0x07060302u);  // [ua.hi16, ub.hi16]
}
static __device__ __forceinline__ bf16x8 cvt8r(float4 v0, float4 v1) {
    union { bf16x8 v; unsigned u[4]; } t;
    t.u[0] = pack_bf2(v0.x, v0.y); t.u[1] = pack_bf2(v0.z, v0.w);
    t.u[2] = pack_bf2(v1.x, v1.y); t.u[3] = pack_bf2(v1.z, v1.w);
    return t.v;
}
static __device__ __forceinline__ float fexp2(float x) {
#if __has_builtin(__builtin_amdgcn_exp2f)
    return __builtin_amdgcn_exp2f(x);
#else
    return exp2f(x);
#endif
}
// async global -> LDS, 16 B per lane (lane i lands at l + 16*i)
static __device__ __forceinline__ void gl_lds16(const float* g, void* l) {
    __builtin_amdgcn_global_load_lds(
        (const __attribute__((address_space(1))) unsigned*)g,
        (__attribute__((address_space(3))) unsigned*)l, 16, 0, 0);
}

// ---------------- prep: W -> bf16 (q rows pre-scaled) ----------------
__global__ __launch_bounds__(256) void prep_kernel(
    const float* __restrict__ Wk, const float* __restrict__ Wq,
    const float* __restrict__ Wv, unsigned short* __restrict__ wbf)
{
    const int idx = blockIdx.x * 256 + threadIdx.x;   // 0..12287 float4s
    const int row = idx >> 6, c4 = (idx & 63) << 2;
    const float* src; float sc = 1.0f;
    if (row < 64)       src = &Wk[(size_t)row * C_];
    else if (row < 128) { src = &Wq[(size_t)(row - 64) * C_]; sc = QSCALE; }
    else                src = &Wv[(size_t)(row - 128) * C_];
    float4 v = *(const float4*)&src[c4];
    uint2 o = make_uint2(pack_bf2(v.x * sc, v.y * sc), pack_bf2(v.z * sc, v.w * sc));
    *(uint2*)&wbf[(size_t)row * C_ + c4] = o;
}

// ---------------- proj: async-staged bf16 MFMA GEMM ----------------
// grid 1024 (32 m-rows each), block 256 = 4 waves; wave w: n in [48w, 48w+48)
#define XPITCH 1040   // bytes per x row in LDS (1024 + 16 pad)
__global__ __launch_bounds__(256) void proj_kernel(
    const float* __restrict__ x, const unsigned short* __restrict__ wbf,
    unsigned short* __restrict__ fqk, unsigned short* __restrict__ vt)
{
    __shared__ __align__(16) char xls[32 * XPITCH];   // 33280 B -> 4 blocks/CU

    const int tid = threadIdx.x;
    const int lane = tid & 63, w = tid >> 6;
    const int q4 = lane >> 4, l15 = lane & 15;
    const int m0 = blockIdx.x * 32;

    // stage: wave w DMAs rows 8w..8w+7 (1 KB per call, contiguous per row)
    {
        const float* gbase = &x[(size_t)(m0 + 8 * w) * C_ + lane * 4];
        #pragma unroll
        for (int j = 0; j < 8; ++j)
            gl_lds16(gbase + (size_t)j * C_, xls + (8 * w + j) * XPITCH);
    }

    // A-frag source rows in wbf (bf16, pre-scaled)
    const unsigned short* wrow = &wbf[(size_t)(48 * w + l15) * C_ + q4 * 8];

    f32x4 acc[3][2];
    #pragma unroll
    for (int nt = 0; nt < 3; ++nt)
        #pragma unroll
        for (int mt = 0; mt < 2; ++mt) acc[nt][mt] = (f32x4)0.0f;

    // prefetch first A-frags (overlaps the DMA)
    bf16x8 aw[3];
    #pragma unroll
    for (int nt = 0; nt < 3; ++nt)
        aw[nt] = *(const bf16x8*)&wrow[(size_t)nt * 16 * C_];

    __syncthreads();   // DMA complete (barrier drains vmcnt)

    #pragma unroll
    for (int ks = 0; ks < 8; ++ks) {
        // B-frags from LDS (fp32 -> bf16 in-reg)
        bf16x8 bx[2];
        #pragma unroll
        for (int mt = 0; mt < 2; ++mt) {
            const float* p = (const float*)(xls + (mt * 16 + l15) * XPITCH
                                            + (ks * 32 + q4 * 8) * 4);
            float4 v0 = *(const float4*)p;
            float4 v1 = *(const float4*)(p + 4);
            bx[mt] = cvt8r(v0, v1);
        }
        bf16x8 awn[3];
        if (ks < 7) {
            #pragma unroll
            for (int nt = 0; nt < 3; ++nt)
                awn[nt] = *(const bf16x8*)&wrow[(size_t)nt * 16 * C_ + (ks + 1) * 32];
        }
        #pragma unroll
        for (int nt = 0; nt < 3; ++nt) {
            acc[nt][0] = __builtin_amdgcn_mfma_f32_16x16x32_bf16(aw[nt], bx[0], acc[nt][0], 0, 0, 0);
            acc[nt][1] = __builtin_amdgcn_mfma_f32_16x16x32_bf16(aw[nt], bx[1], acc[nt][1], 0, 0, 0);
        }
        #pragma unroll
        for (int nt = 0; nt < 3; ++nt) aw[nt] = awn[nt];
    }

    // epilogue: FQK chunk-pair layout (coalesced) | vt transposed (scalar)
    const int mbg = m0 >> 4;
    #pragma unroll
    for (int nt = 0; nt < 3; ++nt) {
        const int c = 48 * w + 16 * nt + 4 * q4;     // output column base (4 wide)
        #pragma unroll
        for (int mt = 0; mt < 2; ++mt) {
            const int m = m0 + mt * 16 + l15;
            f32x4 v = acc[nt][mt];
            if (c < 128) {           // k | q -> FQK[mb][cp][r][8]
                uint2 o = make_uint2(pack_bf2(v.x, v.y), pack_bf2(v.z, v.w));
                *(uint2*)&fqk[(size_t)(mbg + mt) * 2048 + (c >> 3) * 128 + l15 * 8 + (c & 7)] = o;
            } else {                 // v -> transposed vt[b][h][s]
                const int batch = m >> 10, s = m & 1023, h = c - 128;
                vt[((size_t)batch * 64 + h + 0) * 1024 + s] = f2bf(v.x);
                vt[((size_t)batch * 64 + h + 1) * 1024 + s] = f2bf(v.y);
                vt[((size_t)batch * 64 + h + 2) * 1024 + s] = f2bf(v.z);
                vt[((size_t)batch * 64 + h + 3) * 1024 + s] = f2bf(v.w);
            }
        }
    }
}

// ---------------- attention: 4-wave split-s flash, no-max, base-2 ----------------
// grid 1024; XCD-aware swizzle: batch = 4*(bx&7) + (slot&3), qt = 31-(slot>>2)
__global__ __launch_bounds__(256) void attn_kernel(
    const unsigned short* __restrict__ fqk,
    const unsigned short* __restrict__ vt,
    float* __restrict__ out)
{
    __shared__ __align__(16) char smem[34816];   // Ps[4][32][72] (18.4K) U ocomb(32K)+lcomb(2K)

    const int tid = threadIdx.x;
    const int lane = tid & 63, w = tid >> 6;
    const int q4 = lane >> 4, l15 = lane & 15;
    const int slot  = blockIdx.x >> 3;            // 0..127
    const int batch = (blockIdx.x & 7) * 4 + (slot & 3);
    const int qt    = 31 - (slot >> 2);           // heavy-first per XCD
    const int q0    = qt * 32;
    const int ns    = (qt >> 1) + 1;

    unsigned short (*Ps)[72] = (unsigned short(*)[72])(smem + w * 4608);

    const unsigned short* kb2 = &fqk[(size_t)batch * 64 * 2048];
    const unsigned short* vbase = &vt[(size_t)batch * 64 * 1024];

    // Q B-frags: FQK[mb = q0/16+it][cp = 8+4*kc+q4][l15][8] -- b128 coalesced
    bf16x8 qf[2][2];
    #pragma unroll
    for (int it = 0; it < 2; ++it)
        #pragma unroll
        for (int kc = 0; kc < 2; ++kc)
            qf[it][kc] = *(const bf16x8*)&kb2[(size_t)((q0 >> 4) + it) * 2048
                                              + (8 + 4 * kc + q4) * 128 + l15 * 8];

    f32x4 o[4][2];
    #pragma unroll
    for (int ht = 0; ht < 4; ++ht)
        #pragma unroll
        for (int it = 0; it < 2; ++it) o[ht][it] = (f32x4)0.0f;
    float l[2] = {0.f, 0.f};

    for (int st = w; st < ns; st += 4) {
        const int s0 = st * 64;
        const bool last = (st == ns - 1);
        #pragma unroll
        for (int hf = 0; hf < 2; ++hf) {
            const int sh = s0 + hf * 32;
            // K A-frags: FQK[sb][cp = 4*kc+q4][l15][8] -- b128 coalesced
            bf16x8 ak[2][2];
            #pragma unroll
            for (int st16 = 0; st16 < 2; ++st16)
                #pragma unroll
                for (int kc = 0; kc < 2; ++kc)
                    ak[st16][kc] = *(const bf16x8*)&kb2[(size_t)((sh >> 4) + st16) * 2048
                                                        + (4 * kc + q4) * 128 + l15 * 8];
            // V^T A-frags for this half
            bf16x8 av[4];
            #pragma unroll
            for (int ht = 0; ht < 4; ++ht)
                av[ht] = *(const bf16x8*)&vbase[(size_t)(ht * 16 + l15) * 1024 + sh + q4 * 8];
            // S^T = K @ Q^T
            f32x4 s[2][2];
            #pragma unroll
            for (int st16 = 0; st16 < 2; ++st16)
                #pragma unroll
                for (int it = 0; it < 2; ++it) {
                    f32x4 c = (f32x4)0.0f;
                    c = __builtin_amdgcn_mfma_f32_16x16x32_bf16(ak[st16][0], qf[it][0], c, 0, 0, 0);
                    c = __builtin_amdgcn_mfma_f32_16x16x32_bf16(ak[st16][1], qf[it][1], c, 0, 0, 0);
                    s[st16][it] = c;
                }
            // p = 2^s', accumulate l, write P^T (packed b64)
            #pragma unroll
            for (int st16 = 0; st16 < 2; ++st16)
                #pragma unroll
                for (int it = 0; it < 2; ++it) {
                    const int iloc = it * 16 + l15;
                    float p[4];
                    #pragma unroll
                    for (int r = 0; r < 4; ++r) {
                        float pv = fexp2(s[st16][it][r]);
                        if (last) {
                            int sl = sh + st16 * 16 + q4 * 4 + r;
                            if (sl > q0 + iloc) pv = 0.0f;   // causal
                        }
                        p[r] = pv;
                        l[it] += pv;
                    }
                    uint2 pw = make_uint2(pack_bf2(p[0], p[1]), pack_bf2(p[2], p[3]));
                    *(uint2*)&Ps[iloc][hf * 32 + st16 * 16 + q4 * 4] = pw;
                }
            // PV: O^T += V^T @ P^T (single-wave LDS round trip, no barrier)
            #pragma unroll
            for (int it = 0; it < 2; ++it) {
                bf16x8 bp = *(const bf16x8*)&Ps[it * 16 + l15][hf * 32 + q4 * 8];
                #pragma unroll
                for (int ht = 0; ht < 4; ++ht)
                    o[ht][it] = __builtin_amdgcn_mfma_f32_16x16x32_bf16(av[ht], bp, o[ht][it], 0, 0, 0);
            }
        }
    }

    // wave-internal l reduce over quads (disjoint s per quad)
    #pragma unroll
    for (int it = 0; it < 2; ++it) {
        l[it] += __shfl_xor(l[it], 16);
        l[it] += __shfl_xor(l[it], 32);
    }

    __syncthreads();   // all waves done with Ps before combine-buffer reuse
    float4* ocomb = (float4*)smem;                 // [w][ht][it][lane]
    float*  lcomb = (float*)(smem + 32768);        // [w][it][lane]
    #pragma unroll
    for (int ht = 0; ht < 4; ++ht)
        #pragma unroll
        for (int it = 0; it < 2; ++it) {
            f32x4 v = o[ht][it];
            ocomb[((w * 4 + ht) * 2 + it) * 64 + lane] = make_float4(v.x, v.y, v.z, v.w);
        }
    #pragma unroll
    for (int it = 0; it < 2; ++it) lcomb[(w * 2 + it) * 64 + lane] = l[it];
    __syncthreads();

    // wave w reduces head-tile ht = w and stores
    #pragma unroll
    for (int it = 0; it < 2; ++it) {
        float4 a = make_float4(0.f, 0.f, 0.f, 0.f);
        float lt = 0.f;
        #pragma unroll
        for (int src = 0; src < 4; ++src) {
            float4 t = ocomb[((src * 4 + w) * 2 + it) * 64 + lane];
            a.x += t.x; a.y += t.y; a.z += t.z; a.w += t.w;
            lt += lcomb[(src * 2 + it) * 64 + lane];
        }
        float inv = 1.0f / lt;
        float4 res = make_float4(a.x * inv, a.y * inv, a.z * inv, a.w * inv);
        *(float4*)&out[(size_t)(batch * T_ + q0 + it * 16 + l15) * HS_ + w * 16 + q4 * 4] = res;
    }
}

extern "C" void kernel_launch(void* const* d_in, const int* in_sizes, int n_in,
                              void* d_out, int out_size, void* d_ws, size_t ws_size,
                              hipStream_t stream) {
    (void)in_sizes; (void)n_in; (void)out_size; (void)ws_size;
    const float* x  = (const float*)d_in[0];
    const float* Wk = (const float*)d_in[1];
    const float* Wq = (const float*)d_in[2];
    const float* Wv = (const float*)d_in[3];

    unsigned short* wbf = (unsigned short*)d_ws;                                   // 96 KB
    unsigned short* fqk = (unsigned short*)((char*)d_ws + 98304);                  // 8 MB
    unsigned short* vtb = (unsigned short*)((char*)d_ws + 98304 + (size_t)32768 * 128 * 2); // 4 MB

    hipLaunchKernelGGL(prep_kernel, dim3(48),   dim3(256), 0, stream, Wk, Wq, Wv, wbf);
    hipLaunchKernelGGL(proj_kernel, dim3(1024), dim3(256), 0, stream, x, wbf, fqk, vtb);
    hipLaunchKernelGGL(attn_kernel, dim3(1024), dim3(256), 0, stream, fqk, vtb, (float*)d_out);
}

// Round 8
// 106.732 us; speedup vs baseline: 1.2646x; 1.0179x over previous
//
#include <hip/hip_runtime.h>
#include <hip/hip_bf16.h>
#include <math.h>

// B=32, T=1024, C=256, HS=64. fp32 in/out, bf16 MFMA internally.
// prep: W -> bf16 wbf[192][256] (k | q*0.125*log2e | v rows), once (~96 KB).
// proj: x tile staged via async global_load_lds (pitch 1040), W A-frags from
//       L2-hot wbf. Outputs (both frag-major so attn loads are coalesced):
//       FQK [mblk(2048)][cp(16)][r(16)][8] bf16: cols 0..63=k, 64..127=q*scale.
//       VT2 [b][ht(4)][sc(32)][r(16)][8] bf16: V^T A-frags; av load is one
//         contiguous 1 KB segment (R7's vt[b][h][s] made every av b128 a
//         64-segment gather = 4x V over-fetch -- the attn bottleneck).
// attn: 4 waves/block, 32-query tile, s-tiles strided across waves (no-max
//       base-2 flash: combine is a pure sum). XCD swizzle pins each batch's
//       K/V to one XCD's L2. P^T via per-wave LDS, 2 barriers/block.

#define B_  32
#define T_  1024
#define C_  256
#define HS_ 64
#define QSCALE 0.1803368801111204f   // 0.125 * log2(e)

typedef __attribute__((ext_vector_type(8))) short bf16x8;
typedef __attribute__((ext_vector_type(4))) float f32x4;

static __device__ __forceinline__ unsigned short f2bf(float f) {
    unsigned u = __builtin_bit_cast(unsigned, f);
    u += 0x7FFFu + ((u >> 16) & 1u);               // RNE
    return (unsigned short)(u >> 16);
}
// pack two floats to packed bf16 pair (round-half-up; 2 adds + 1 v_perm)
static __device__ __forceinline__ unsigned pack_bf2(float a, float b) {
    unsigned ua = __builtin_bit_cast(unsigned, a) + 0x8000u;
    unsigned ub = __builtin_bit_cast(unsigned, b) + 0x8000u;
    return __builtin_amdgcn_perm(ub, ua, 0x07060302u);  // [ua.hi16, ub.hi16]
}
static __device__ __forceinline__ bf16x8 cvt8r(float4 v0, float4 v1) {
    union { bf16x8 v; unsigned u[4]; } t;
    t.u[0] = pack_bf2(v0.x, v0.y); t.u[1] = pack_bf2(v0.z, v0.w);
    t.u[2] = pack_bf2(v1.x, v1.y); t.u[3] = pack_bf2(v1.z, v1.w);
    return t.v;
}
static __device__ __forceinline__ float fexp2(float x) {
#if __has_builtin(__builtin_amdgcn_exp2f)
    return __builtin_amdgcn_exp2f(x);
#else
    return exp2f(x);
#endif
}
// async global -> LDS, 16 B per lane (lane i lands at l + 16*i)
static __device__ __forceinline__ void gl_lds16(const float* g, void* l) {
    __builtin_amdgcn_global_load_lds(
        (const __attribute__((address_space(1))) unsigned*)g,
        (__attribute__((address_space(3))) unsigned*)l, 16, 0, 0);
}

// ---------------- prep: W -> bf16 (q rows pre-scaled) ----------------
__global__ __launch_bounds__(256) void prep_kernel(
    const float* __restrict__ Wk, const float* __restrict__ Wq,
    const float* __restrict__ Wv, unsigned short* __restrict__ wbf)
{
    const int idx = blockIdx.x * 256 + threadIdx.x;   // 0..12287 float4s
    const int row = idx >> 6, c4 = (idx & 63) << 2;
    const float* src; float sc = 1.0f;
    if (row < 64)       src = &Wk[(size_t)row * C_];
    else if (row < 128) { src = &Wq[(size_t)(row - 64) * C_]; sc = QSCALE; }
    else                src = &Wv[(size_t)(row - 128) * C_];
    float4 v = *(const float4*)&src[c4];
    uint2 o = make_uint2(pack_bf2(v.x * sc, v.y * sc), pack_bf2(v.z * sc, v.w * sc));
    *(uint2*)&wbf[(size_t)row * C_ + c4] = o;
}

// ---------------- proj: async-staged bf16 MFMA GEMM ----------------
// grid 1024 (32 m-rows each), block 256 = 4 waves; wave w: n in [48w, 48w+48)
#define XPITCH 1040   // bytes per x row in LDS (1024 + 16 pad)
__global__ __launch_bounds__(256) void proj_kernel(
    const float* __restrict__ x, const unsigned short* __restrict__ wbf,
    unsigned short* __restrict__ fqk, unsigned short* __restrict__ vt2)
{
    __shared__ __align__(16) char xls[32 * XPITCH];   // 33280 B -> 4 blocks/CU

    const int tid = threadIdx.x;
    const int lane = tid & 63, w = tid >> 6;
    const int q4 = lane >> 4, l15 = lane & 15;
    const int m0 = blockIdx.x * 32;

    // stage: wave w DMAs rows 8w..8w+7 (1 KB per call, contiguous per row)
    {
        const float* gbase = &x[(size_t)(m0 + 8 * w) * C_ + lane * 4];
        #pragma unroll
        for (int j = 0; j < 8; ++j)
            gl_lds16(gbase + (size_t)j * C_, xls + (8 * w + j) * XPITCH);
    }

    // A-frag source rows in wbf (bf16, pre-scaled)
    const unsigned short* wrow = &wbf[(size_t)(48 * w + l15) * C_ + q4 * 8];

    f32x4 acc[3][2];
    #pragma unroll
    for (int nt = 0; nt < 3; ++nt)
        #pragma unroll
        for (int mt = 0; mt < 2; ++mt) acc[nt][mt] = (f32x4)0.0f;

    // prefetch first A-frags (overlaps the DMA)
    bf16x8 aw[3];
    #pragma unroll
    for (int nt = 0; nt < 3; ++nt)
        aw[nt] = *(const bf16x8*)&wrow[(size_t)nt * 16 * C_];

    __syncthreads();   // DMA complete (barrier drains vmcnt)

    #pragma unroll
    for (int ks = 0; ks < 8; ++ks) {
        // B-frags from LDS (fp32 -> bf16 in-reg)
        bf16x8 bx[2];
        #pragma unroll
        for (int mt = 0; mt < 2; ++mt) {
            const float* p = (const float*)(xls + (mt * 16 + l15) * XPITCH
                                            + (ks * 32 + q4 * 8) * 4);
            float4 v0 = *(const float4*)p;
            float4 v1 = *(const float4*)(p + 4);
            bx[mt] = cvt8r(v0, v1);
        }
        bf16x8 awn[3];
        if (ks < 7) {
            #pragma unroll
            for (int nt = 0; nt < 3; ++nt)
                awn[nt] = *(const bf16x8*)&wrow[(size_t)nt * 16 * C_ + (ks + 1) * 32];
        }
        #pragma unroll
        for (int nt = 0; nt < 3; ++nt) {
            acc[nt][0] = __builtin_amdgcn_mfma_f32_16x16x32_bf16(aw[nt], bx[0], acc[nt][0], 0, 0, 0);
            acc[nt][1] = __builtin_amdgcn_mfma_f32_16x16x32_bf16(aw[nt], bx[1], acc[nt][1], 0, 0, 0);
        }
        #pragma unroll
        for (int nt = 0; nt < 3; ++nt) aw[nt] = awn[nt];
    }

    // epilogue: FQK chunk-pair (coalesced) | VT2 frag-major (32B-run scalars)
    const int mbg = m0 >> 4;
    #pragma unroll
    for (int nt = 0; nt < 3; ++nt) {
        const int c = 48 * w + 16 * nt + 4 * q4;     // output column base (4 wide)
        #pragma unroll
        for (int mt = 0; mt < 2; ++mt) {
            const int m = m0 + mt * 16 + l15;
            f32x4 v = acc[nt][mt];
            if (c < 128) {           // k | q -> FQK[mb][cp][r][8]
                uint2 o = make_uint2(pack_bf2(v.x, v.y), pack_bf2(v.z, v.w));
                *(uint2*)&fqk[(size_t)(mbg + mt) * 2048 + (c >> 3) * 128 + l15 * 8 + (c & 7)] = o;
            } else {                 // v -> VT2[b][ht][sc][r(16)][8]
                const int batch = m >> 10, s = m & 1023;
                const int hb = c - 128;              // 4-aligned, 0..63
                const int ht = hb >> 4, rb = hb & 15;
                const int sc = s >> 5, kk = s & 31;
                unsigned short* dst = &vt2[((((size_t)batch * 4 + ht) * 32 + sc) * 16) * 32
                                           + rb * 32 + kk];
                dst[0 * 32] = f2bf(v.x);
                dst[1 * 32] = f2bf(v.y);
                dst[2 * 32] = f2bf(v.z);
                dst[3 * 32] = f2bf(v.w);
            }
        }
    }
}

// ---------------- attention: 4-wave split-s flash, no-max, base-2 ----------------
// grid 1024; XCD-aware swizzle: batch = 4*(bx&7) + (slot&3), qt = 31-(slot>>2)
__global__ __launch_bounds__(256) void attn_kernel(
    const unsigned short* __restrict__ fqk,
    const unsigned short* __restrict__ vt2,
    float* __restrict__ out)
{
    __shared__ __align__(16) char smem[34816];   // Ps[4][32][72] (18.4K) U ocomb(32K)+lcomb(2K)

    const int tid = threadIdx.x;
    const int lane = tid & 63, w = tid >> 6;
    const int q4 = lane >> 4, l15 = lane & 15;
    const int slot  = blockIdx.x >> 3;            // 0..127
    const int batch = (blockIdx.x & 7) * 4 + (slot & 3);
    const int qt    = 31 - (slot >> 2);           // heavy-first per XCD
    const int q0    = qt * 32;
    const int ns    = (qt >> 1) + 1;

    unsigned short (*Ps)[72] = (unsigned short(*)[72])(smem + w * 4608);

    const unsigned short* kb2 = &fqk[(size_t)batch * 64 * 2048];
    const unsigned short* vb2 = &vt2[(size_t)batch * 4 * 32 * 512];

    // Q B-frags: FQK[mb = q0/16+it][cp = 8+4*kc+q4][l15][8] -- b128 coalesced
    bf16x8 qf[2][2];
    #pragma unroll
    for (int it = 0; it < 2; ++it)
        #pragma unroll
        for (int kc = 0; kc < 2; ++kc)
            qf[it][kc] = *(const bf16x8*)&kb2[(size_t)((q0 >> 4) + it) * 2048
                                              + (8 + 4 * kc + q4) * 128 + l15 * 8];

    f32x4 o[4][2];
    #pragma unroll
    for (int ht = 0; ht < 4; ++ht)
        #pragma unroll
        for (int it = 0; it < 2; ++it) o[ht][it] = (f32x4)0.0f;
    float l[2] = {0.f, 0.f};

    for (int st = w; st < ns; st += 4) {
        const int s0 = st * 64;
        const bool last = (st == ns - 1);
        #pragma unroll
        for (int hf = 0; hf < 2; ++hf) {
            const int sh = s0 + hf * 32;
            // K A-frags: FQK[sb][cp = 4*kc+q4][l15][8] -- b128 coalesced
            bf16x8 ak[2][2];
            #pragma unroll
            for (int st16 = 0; st16 < 2; ++st16)
                #pragma unroll
                for (int kc = 0; kc < 2; ++kc)
                    ak[st16][kc] = *(const bf16x8*)&kb2[(size_t)((sh >> 4) + st16) * 2048
                                                        + (4 * kc + q4) * 128 + l15 * 8];
            // V^T A-frags: VT2[ht][sc=sh/32][l15][q4*8] -- one 1 KB segment
            bf16x8 av[4];
            #pragma unroll
            for (int ht = 0; ht < 4; ++ht)
                av[ht] = *(const bf16x8*)&vb2[((size_t)ht * 32 + (sh >> 5)) * 512
                                               + l15 * 32 + q4 * 8];
            // S^T = K @ Q^T
            f32x4 s[2][2];
            #pragma unroll
            for (int st16 = 0; st16 < 2; ++st16)
                #pragma unroll
                for (int it = 0; it < 2; ++it) {
                    f32x4 c = (f32x4)0.0f;
                    c = __builtin_amdgcn_mfma_f32_16x16x32_bf16(ak[st16][0], qf[it][0], c, 0, 0, 0);
                    c = __builtin_amdgcn_mfma_f32_16x16x32_bf16(ak[st16][1], qf[it][1], c, 0, 0, 0);
                    s[st16][it] = c;
                }
            // p = 2^s', accumulate l, write P^T (packed b64)
            #pragma unroll
            for (int st16 = 0; st16 < 2; ++st16)
                #pragma unroll
                for (int it = 0; it < 2; ++it) {
                    const int iloc = it * 16 + l15;
                    float p[4];
                    #pragma unroll
                    for (int r = 0; r < 4; ++r) {
                        float pv = fexp2(s[st16][it][r]);
                        if (last) {
                            int sl = sh + st16 * 16 + q4 * 4 + r;
                            if (sl > q0 + iloc) pv = 0.0f;   // causal
                        }
                        p[r] = pv;
                        l[it] += pv;
                    }
                    uint2 pw = make_uint2(pack_bf2(p[0], p[1]), pack_bf2(p[2], p[3]));
                    *(uint2*)&Ps[iloc][hf * 32 + st16 * 16 + q4 * 4] = pw;
                }
            // PV: O^T += V^T @ P^T (single-wave LDS round trip, no barrier)
            #pragma unroll
            for (int it = 0; it < 2; ++it) {
                bf16x8 bp = *(const bf16x8*)&Ps[it * 16 + l15][hf * 32 + q4 * 8];
                #pragma unroll
                for (int ht = 0; ht < 4; ++ht)
                    o[ht][it] = __builtin_amdgcn_mfma_f32_16x16x32_bf16(av[ht], bp, o[ht][it], 0, 0, 0);
            }
        }
    }

    // wave-internal l reduce over quads (disjoint s per quad)
    #pragma unroll
    for (int it = 0; it < 2; ++it) {
        l[it] += __shfl_xor(l[it], 16);
        l[it] += __shfl_xor(l[it], 32);
    }

    __syncthreads();   // all waves done with Ps before combine-buffer reuse
    float4* ocomb = (float4*)smem;                 // [w][ht][it][lane]
    float*  lcomb = (float*)(smem + 32768);        // [w][it][lane]
    #pragma unroll
    for (int ht = 0; ht < 4; ++ht)
        #pragma unroll
        for (int it = 0; it < 2; ++it) {
            f32x4 v = o[ht][it];
            ocomb[((w * 4 + ht) * 2 + it) * 64 + lane] = make_float4(v.x, v.y, v.z, v.w);
        }
    #pragma unroll
    for (int it = 0; it < 2; ++it) lcomb[(w * 2 + it) * 64 + lane] = l[it];
    __syncthreads();

    // wave w reduces head-tile ht = w and stores
    #pragma unroll
    for (int it = 0; it < 2; ++it) {
        float4 a = make_float4(0.f, 0.f, 0.f, 0.f);
        float lt = 0.f;
        #pragma unroll
        for (int src = 0; src < 4; ++src) {
            float4 t = ocomb[((src * 4 + w) * 2 + it) * 64 + lane];
            a.x += t.x; a.y += t.y; a.z += t.z; a.w += t.w;
            lt += lcomb[(src * 2 + it) * 64 + lane];
        }
        float inv = 1.0f / lt;
        float4 res = make_float4(a.x * inv, a.y * inv, a.z * inv, a.w * inv);
        *(float4*)&out[(size_t)(batch * T_ + q0 + it * 16 + l15) * HS_ + w * 16 + q4 * 4] = res;
    }
}

extern "C" void kernel_launch(void* const* d_in, const int* in_sizes, int n_in,
                              void* d_out, int out_size, void* d_ws, size_t ws_size,
                              hipStream_t stream) {
    (void)in_sizes; (void)n_in; (void)out_size; (void)ws_size;
    const float* x  = (const float*)d_in[0];
    const float* Wk = (const float*)d_in[1];
    const float* Wq = (const float*)d_in[2];
    const float* Wv = (const float*)d_in[3];

    unsigned short* wbf = (unsigned short*)d_ws;                                   // 96 KB
    unsigned short* fqk = (unsigned short*)((char*)d_ws + 98304);                  // 8 MB
    unsigned short* vt2 = (unsigned short*)((char*)d_ws + 98304 + (size_t)32768 * 128 * 2); // 4 MB

    hipLaunchKernelGGL(prep_kernel, dim3(48),   dim3(256), 0, stream, Wk, Wq, Wv, wbf);
    hipLaunchKernelGGL(proj_kernel, dim3(1024), dim3(256), 0, stream, x, wbf, fqk, vt2);
    hipLaunchKernelGGL(attn_kernel, dim3(1024), dim3(256), 0, stream, fqk, vt2, (float*)d_out);
}